// Round 13
// baseline (306.126 us; speedup 1.0000x reference)
//
#include <hip/hip_runtime.h>

#define HH 512
#define WW 512
#define BB 2
#define CKXY 0.3125f   /* COMPACT / sqrt(H*W/NSUP) = 10/32 */
#define HW (HH*WW)

typedef short bf16x8 __attribute__((ext_vector_type(8)));
typedef float f32x4  __attribute__((ext_vector_type(4)));

__device__ __forceinline__ unsigned short f2bf(float f) {
  unsigned u = __float_as_uint(f);
  u += 0x7FFF + ((u >> 16) & 1);   // round-to-nearest-even
  return (unsigned short)(u >> 16);
}
__device__ __forceinline__ unsigned pack2(float lo, float hi) {
  return (unsigned)f2bf(lo) | ((unsigned)f2bf(hi) << 16);
}

// ---------------- MFMA conv 3x3 CIN->10 (+relu), 32x16 tile, 512 thr.
// LDS [18][34][16ch] bf16 = 19.6 KB -> 4 blocks/CU (32 waves/CU).
// 5 MFMA per 16-px tile (K=32 = 2 taps x 16 ci). Output: bf16 pair-planes.
template<int CIN, bool BF16IN>
__global__ __launch_bounds__(512) void conv_mfma_u(const void* __restrict__ in,
    const float* __restrict__ w, const float* __restrict__ bias,
    unsigned* __restrict__ outu) {
  const int bx = blockIdx.x, by = blockIdx.y, b = blockIdx.z;
  const int tid = threadIdx.x;
  const int gy0 = by * 16, gx0 = bx * 32;
  __shared__ unsigned short sT[18 * 34 * 16];

  const int lane = tid & 63;
  const int g = lane >> 4;        // k-quarter 0..3
  const int co = lane & 15;       // output channel col
  bf16x8 Bf[5];
  #pragma unroll
  for (int P = 0; P < 5; ++P) {
    #pragma unroll
    for (int j = 0; j < 8; ++j) {
      const int tap = 2 * P + (g >> 1);
      const int ci = ((g & 1) << 3) + j;
      unsigned short v = 0;
      if (co < 10 && ci < CIN && tap < 9)
        v = f2bf(w[(co * CIN + ci) * 9 + tap]);
      Bf[P][j] = (short)v;
    }
  }
  const float bs = (co < 10) ? bias[co] : 0.f;

  // ---- stage tile (halo included) as [py][px][16ch] bf16
  for (int p = tid; p < 18 * 34; p += 512) {
    const int ly = p / 34, lx = p - ly * 34;
    const int gy = gy0 + ly - 1, gx = gx0 + lx - 1;
    const bool ok = ((unsigned)gy < HH) && ((unsigned)gx < WW);
    const int pix = gy * WW + gx;
    unsigned u[8];
    if (BF16IN) {
      const unsigned* pp = (const unsigned*)in + (size_t)b * 5 * HW + pix;
      #pragma unroll
      for (int c2 = 0; c2 < 8; ++c2)
        u[c2] = (c2 < (CIN + 1) / 2 && ok) ? pp[c2 * HW] : 0u;
    } else {
      const float* pp = (const float*)in + (size_t)b * CIN * HW + pix;
      #pragma unroll
      for (int c2 = 0; c2 < 8; ++c2) {
        float f0 = (2 * c2 < CIN && ok) ? pp[(2 * c2) * HW] : 0.f;
        float f1 = (2 * c2 + 1 < CIN && ok) ? pp[(2 * c2 + 1) * HW] : 0.f;
        u[c2] = pack2(f0, f1);
      }
    }
    uint4* dst = reinterpret_cast<uint4*>(&sT[p * 16]);
    dst[0] = make_uint4(u[0], u[1], u[2], u[3]);
    dst[1] = make_uint4(u[4], u[5], u[6], u[7]);
  }
  __syncthreads();

  // ---- compute: 32 px-tiles (16 rows x 2 halves), 4 per wave
  const int wave = tid >> 6;
  unsigned* ob = outu + (size_t)b * 5 * HW;
  for (int i = 0; i < 4; ++i) {
    const int t = wave * 4 + i;
    const int py = t >> 1;
    const int pxb = (t & 1) << 4;
    f32x4 acc = {bs, bs, bs, bs};
    #pragma unroll
    for (int P = 0; P < 5; ++P) {
      int tap = 2 * P + (g >> 1);
      if (tap > 8) tap = 8;         // phantom tap: B=0 there
      const int dy = tap / 3 - 1, dx = tap % 3 - 1;
      const int m = lane & 15;
      const int addr = ((py + 1 + dy) * 34 + (pxb + m + 1 + dx)) * 16 + ((g & 1) << 3);
      bf16x8 a = *reinterpret_cast<const bf16x8*>(&sT[addr]);
      acc = __builtin_amdgcn_mfma_f32_16x16x32_bf16(a, Bf[P], acc, 0, 0, 0);
    }
    float o0 = fmaxf(acc[0], 0.f), o1 = fmaxf(acc[1], 0.f);
    float o2 = fmaxf(acc[2], 0.f), o3 = fmaxf(acc[3], 0.f);
    const float q0 = __shfl_xor(o0, 1), q1 = __shfl_xor(o1, 1);
    const float q2 = __shfl_xor(o2, 1), q3 = __shfl_xor(o3, 1);
    if (!(co & 1) && co < 10) {
      const int y = gy0 + py;
      const int x = gx0 + pxb + (g << 2);
      uint4 st;
      st.x = pack2(o0, q0); st.y = pack2(o1, q1);
      st.z = pack2(o2, q2); st.w = pack2(o3, q3);
      *reinterpret_cast<uint4*>(&ob[(co >> 1) * HW + y * WW + x]) = st;
    }
  }
}

// ---------------- final conv (10->5) via MFMA + bf16 imfeat build + cent0
// 32x32 tile (block == SSN cell). imfeat = 5 bf16-pair dword planes:
// p0=(c0,c1) p1=(c2,c3) p2=(c4,X0) p3=(X1,X2) p4=(x*ck,y*ck)
__global__ __launch_bounds__(512) void conv_final_mfma(const unsigned* __restrict__ in,
    const float* __restrict__ w, const float* __restrict__ bias,
    const float* __restrict__ X, unsigned* __restrict__ imfeat,
    float* __restrict__ cent0) {
  const int bx = blockIdx.x, by = blockIdx.y, b = blockIdx.z;
  const int tid = threadIdx.x;
  const int gy0 = by * 32, gx0 = bx * 32;
  __shared__ unsigned short sT[34 * 34 * 16];
  __shared__ float sC[8][5];
  __shared__ float sX[8][3];

  const int lane = tid & 63;
  const int g = lane >> 4;
  const int co = lane & 15;
  bf16x8 Bf[5];
  #pragma unroll
  for (int P = 0; P < 5; ++P) {
    #pragma unroll
    for (int j = 0; j < 8; ++j) {
      const int tap = 2 * P + (g >> 1);
      const int ci = ((g & 1) << 3) + j;
      unsigned short v = 0;
      if (co < 5 && ci < 10 && tap < 9)
        v = f2bf(w[(co * 10 + ci) * 9 + tap]);
      Bf[P][j] = (short)v;
    }
  }
  const float bs = (co < 5) ? bias[co] : 0.f;

  for (int p = tid; p < 34 * 34; p += 512) {
    const int ly = p / 34, lx = p - ly * 34;
    const int gy = gy0 + ly - 1, gx = gx0 + lx - 1;
    const bool ok = ((unsigned)gy < HH) && ((unsigned)gx < WW);
    const unsigned* pp = in + (size_t)b * 5 * HW + gy * WW + gx;
    unsigned u[5];
    #pragma unroll
    for (int c2 = 0; c2 < 5; ++c2) u[c2] = ok ? pp[c2 * HW] : 0u;
    uint4* dst = reinterpret_cast<uint4*>(&sT[p * 16]);
    dst[0] = make_uint4(u[0], u[1], u[2], u[3]);
    dst[1] = make_uint4(u[4], 0u, 0u, 0u);
  }
  __syncthreads();

  const int wave = tid >> 6;
  unsigned* ob = imfeat + (size_t)b * 5 * HW;
  const float* Xb = X + (size_t)b * 3 * HW;
  float cSum = 0.f;
  for (int i = 0; i < 8; ++i) {
    const int t = wave * 8 + i;
    const int py = t >> 1;
    const int pxb = (t & 1) << 4;
    f32x4 acc = {bs, bs, bs, bs};
    #pragma unroll
    for (int P = 0; P < 5; ++P) {
      int tap = 2 * P + (g >> 1);
      if (tap > 8) tap = 8;
      const int dy = tap / 3 - 1, dx = tap % 3 - 1;
      const int m = lane & 15;
      const int addr = ((py + 1 + dy) * 34 + (pxb + m + 1 + dx)) * 16 + ((g & 1) << 3);
      bf16x8 a = *reinterpret_cast<const bf16x8*>(&sT[addr]);
      acc = __builtin_amdgcn_mfma_f32_16x16x32_bf16(a, Bf[P], acc, 0, 0, 0);
    }
    const int y = gy0 + py;
    const int x = gx0 + pxb + (g << 2);
    const float q0 = __shfl_xor(acc[0], 1), q1 = __shfl_xor(acc[1], 1);
    const float q2 = __shfl_xor(acc[2], 1), q3 = __shfl_xor(acc[3], 1);
    if (co == 0 || co == 2) {        // planes 0,1 = (c0,c1),(c2,c3)
      uint4 st;
      st.x = pack2(acc[0], q0); st.y = pack2(acc[1], q1);
      st.z = pack2(acc[2], q2); st.w = pack2(acc[3], q3);
      *reinterpret_cast<uint4*>(&ob[(co >> 1) * HW + y * WW + x]) = st;
    } else if (co == 4) {            // plane 2 = (c4, X0)
      float4 xv = *reinterpret_cast<const float4*>(&Xb[y * WW + x]);
      uint4 st;
      st.x = pack2(acc[0], xv.x); st.y = pack2(acc[1], xv.y);
      st.z = pack2(acc[2], xv.z); st.w = pack2(acc[3], xv.w);
      *reinterpret_cast<uint4*>(&ob[2 * HW + y * WW + x]) = st;
    }
    cSum += acc[0] + acc[1] + acc[2] + acc[3];
  }
  cSum += __shfl_xor(cSum, 16);
  cSum += __shfl_xor(cSum, 32);
  if (lane < 5) sC[wave][lane] = cSum;

  // planes 3,4 + X sums (2 px per thread)
  float xs[3] = {0.f, 0.f, 0.f};
  for (int p = tid; p < 1024; p += 512) {
    const int y = gy0 + (p >> 5), x = gx0 + (p & 31);
    const int pix = y * WW + x;
    float x0 = Xb[pix];
    float x1 = Xb[HW + pix];
    float x2 = Xb[2 * HW + pix];
    xs[0] += x0; xs[1] += x1; xs[2] += x2;
    ob[3 * HW + pix] = pack2(x1, x2);
    ob[4 * HW + pix] = pack2((float)x * CKXY, (float)y * CKXY);
  }
  #pragma unroll
  for (int off = 32; off; off >>= 1) {
    #pragma unroll
    for (int c = 0; c < 3; ++c) xs[c] += __shfl_down(xs[c], off);
  }
  if (lane == 0) {
    #pragma unroll
    for (int c = 0; c < 3; ++c) sX[wave][c] = xs[c];
  }
  __syncthreads();
  if (tid < 5) {
    float s = 0.f;
    #pragma unroll
    for (int wv = 0; wv < 8; ++wv) s += sC[wv][tid];
    cent0[((b * 10 + tid) * 16 + by) * 16 + bx] = s * (1.0f / 1024.0f);
  }
  if (tid >= 64 && tid < 67) {
    const int c = tid - 64;
    float s = 0.f;
    #pragma unroll
    for (int wv = 0; wv < 8; ++wv) s += sX[wv][c];
    cent0[((b * 10 + 5 + c) * 16 + by) * 16 + bx] = s * (1.0f / 1024.0f);
  }
  if (tid == 128) cent0[((b * 10 + 8) * 16 + by) * 16 + bx] = ((float)gx0 + 15.5f) * CKXY;
  if (tid == 129) cent0[((b * 10 + 9) * 16 + by) * 16 + bx] = ((float)gy0 + 15.5f) * CKXY;
}

// -------------------- SSN iteration: bf16 imfeat in, aff + block sums
__global__ __launch_bounds__(256) void iter2(const unsigned* __restrict__ imfeat,
    const float* __restrict__ centIn, const float* __restrict__ numP,
    const float* __restrict__ denP, float* __restrict__ numO,
    float* __restrict__ denO, float* __restrict__ affO) {
  const int cx = blockIdx.x, cy = blockIdx.y, b = blockIdx.z;
  const int tid = threadIdx.x;
  __shared__ float sc[9][10];
  __shared__ float nb[9][11];
  if (centIn) {
    if (tid < 90) {
      int s = tid / 10, ch = tid - s * 10;
      int dr = s / 3 - 1, dc = s % 3 - 1;
      int r = min(max(cy + dr, 0), 15), c = min(max(cx + dc, 0), 15);
      sc[s][ch] = centIn[((b * 10 + ch) * 16 + r) * 16 + c];
    }
    __syncthreads();
  } else {
    if (tid < 99) {
      int s = tid / 11, j = tid - s * 11;
      int dr = s / 3 - 1, dc = s % 3 - 1;
      int r = min(max(cy + dr, 0), 15), c = min(max(cx + dc, 0), 15);
      float a = 0.f;
      #pragma unroll
      for (int rr = -1; rr <= 1; ++rr)
        #pragma unroll
        for (int cc = -1; cc <= 1; ++cc) {
          int R = r + rr, C = c + cc;
          if ((unsigned)R < 16u && (unsigned)C < 16u)
            a += (j < 10) ? numP[((b * 10 + j) * 16 + R) * 16 + C]
                          : denP[(b * 16 + R) * 16 + C];
        }
      nb[s][j] = a;
    }
    __syncthreads();
    if (tid < 90) {
      int s = tid / 10, ch = tid - s * 10;
      sc[s][ch] = nb[s][ch] / nb[s][10];
    }
    __syncthreads();
  }

  float accN[10];
  #pragma unroll
  for (int ch = 0; ch < 10; ++ch) accN[ch] = 0.f;
  float accD = 0.f;
  const int col = tid & 31, row0 = tid >> 5;
  for (int p = 0; p < 4; ++p) {
    const int y = cy * 32 + row0 + p * 8;
    const int x = cx * 32 + col;
    const unsigned* fb = imfeat + (size_t)b * 5 * HW + y * WW + x;
    float f[10];
    #pragma unroll
    for (int c2 = 0; c2 < 5; ++c2) {
      unsigned u = fb[c2 * HW];
      f[2 * c2]     = __uint_as_float(u << 16);
      f[2 * c2 + 1] = __uint_as_float(u & 0xFFFF0000u);
    }
    float asum = 0.f;
    #pragma unroll
    for (int s = 0; s < 9; ++s) {
      float ss = 0.f;
      #pragma unroll
      for (int ch = 0; ch < 10; ++ch) { float d = f[ch] - sc[s][ch]; ss = fmaf(d, d, ss); }
      float a = __expf(-ss * (1.0f / 1000.0f));
      asum += a;
      if (affO) affO[((b * 9 + s) * HH + y) * WW + x] = a;
    }
    accD += asum;
    #pragma unroll
    for (int ch = 0; ch < 10; ++ch) accN[ch] = fmaf(f[ch], asum, accN[ch]);
  }
  #pragma unroll
  for (int off = 32; off; off >>= 1) {
    accD += __shfl_down(accD, off);
    #pragma unroll
    for (int ch = 0; ch < 10; ++ch) accN[ch] += __shfl_down(accN[ch], off);
  }
  __shared__ float sPart[4][11];
  const int wave = tid >> 6, lane = tid & 63;
  if (lane == 0) {
    #pragma unroll
    for (int ch = 0; ch < 10; ++ch) sPart[wave][ch] = accN[ch];
    sPart[wave][10] = accD;
  }
  __syncthreads();
  if (tid < 11) {
    float s = sPart[0][tid] + sPart[1][tid] + sPart[2][tid] + sPart[3][tid];
    if (tid < 10) numO[((b * 10 + tid) * 16 + cy) * 16 + cx] = s;
    else denO[(b * 16 + cy) * 16 + cx] = s;
  }
}

// ------------------------------- final cent = box3(num)/box3(den) -> output
__global__ __launch_bounds__(256) void cent_final(const float* __restrict__ num_bs,
    const float* __restrict__ den_bs, float* __restrict__ out_cent) {
  const int b = blockIdx.x;
  const int tid = threadIdx.x;
  const int cy = tid >> 4, cx = tid & 15;
  float den = 0.f;
  #pragma unroll
  for (int dr = -1; dr <= 1; ++dr)
    #pragma unroll
    for (int dc = -1; dc <= 1; ++dc) {
      int r = cy + dr, c = cx + dc;
      if ((unsigned)r < 16 && (unsigned)c < 16) den += den_bs[(b * 16 + r) * 16 + c];
    }
  #pragma unroll
  for (int ch = 0; ch < 10; ++ch) {
    float num = 0.f;
    #pragma unroll
    for (int dr = -1; dr <= 1; ++dr)
      #pragma unroll
      for (int dc = -1; dc <= 1; ++dc) {
        int r = cy + dr, c = cx + dc;
        if ((unsigned)r < 16 && (unsigned)c < 16)
          num += num_bs[((b * 10 + ch) * 16 + r) * 16 + c];
      }
    float invck = (ch >= 8) ? (1.0f / CKXY) : 1.0f;
    out_cent[((b * 10 + ch) * 16 + cy) * 16 + cx] = (num / den) * invck;
  }
}

// ---------------------------------------------------------------------------
extern "C" void kernel_launch(void* const* d_in, const int* in_sizes, int n_in,
                              void* d_out, int out_size, void* d_ws, size_t ws_size,
                              hipStream_t stream) {
  const float* X      = (const float*)d_in[0];
  const float* w0     = (const float*)d_in[1];
  const float* b0     = (const float*)d_in[2];
  const float* ws_mid = (const float*)d_in[3];
  const float* bs_mid = (const float*)d_in[4];
  const float* wf     = (const float*)d_in[5];
  const float* bf     = (const float*)d_in[6];
  float* out = (float*)d_out;

  const size_t uplane = (size_t)BB * 5 * HW;    // bf16 pair-planes (dwords)
  unsigned* uA     = (unsigned*)d_ws;
  unsigned* uB     = uA + uplane;
  unsigned* imfeat = uB + uplane;
  float* num0      = (float*)(imfeat + uplane);
  float* den0      = num0 + BB * 10 * 256;
  float* num1      = den0 + BB * 256;
  float* den1      = num1 + BB * 10 * 256;
  float* centA     = den1 + BB * 256;

  dim3 cgrid(16, 32, BB);   // 32x16 tiles
  conv_mfma_u<3, false><<<cgrid, 512, 0, stream>>>(X, w0, b0, uA);
  const unsigned* cur = uA;
  unsigned* nxt = uB;
  for (int l = 0; l < 8; ++l) {
    conv_mfma_u<10, true><<<cgrid, 512, 0, stream>>>(cur, ws_mid + l * 900, bs_mid + l * 10, nxt);
    const unsigned* t = cur; cur = nxt; nxt = (unsigned*)t;
  }
  // cur == uA after 8 swaps
  dim3 fgrid(16, 16, BB);   // 32x32 cells
  conv_final_mfma<<<fgrid, 512, 0, stream>>>(cur, wf, bf, X, imfeat, centA);

  float* aff_out = out + BB * 10 * 256;  // cent (5120) then aff
  float* nums[2] = {num0, num1};
  float* dens[2] = {den0, den1};
  for (int k = 0; k < 10; ++k) {
    iter2<<<fgrid, 256, 0, stream>>>(imfeat,
        (k == 0) ? centA : nullptr,
        (k == 0) ? nullptr : nums[(k - 1) & 1],
        (k == 0) ? nullptr : dens[(k - 1) & 1],
        nums[k & 1], dens[k & 1],
        (k == 9) ? aff_out : nullptr);
  }
  cent_final<<<dim3(BB), 256, 0, stream>>>(nums[1], dens[1], out);
}

// Round 16
// 259.818 us; speedup vs baseline: 1.1782x; 1.1782x over previous
//
#include <hip/hip_runtime.h>

#define HH 512
#define WW 512
#define BB 2
#define CKXY 0.3125f   /* COMPACT / sqrt(H*W/NSUP) = 10/32 */
#define HW (HH*WW)

typedef short bf16x8 __attribute__((ext_vector_type(8)));
typedef float f32x4  __attribute__((ext_vector_type(4)));

__device__ __forceinline__ unsigned short f2bf(float f) {
  unsigned u = __float_as_uint(f);
  u += 0x7FFF + ((u >> 16) & 1);   // round-to-nearest-even
  return (unsigned short)(u >> 16);
}
__device__ __forceinline__ unsigned pack2(float lo, float hi) {
  return (unsigned)f2bf(lo) | ((unsigned)f2bf(hi) << 16);
}

// ---------------- MFMA conv 3x3 CIN->10 (+relu), 32x32 tile, 512 thr (r11-proven).
// LDS [34][34][16ch] bf16 = 37 KB. 5 MFMA per 16-px tile (K=32 = 2 taps x 16 ci).
// Output: bf16 pair-planes (5 dword planes), channel pairs merged via shfl_xor(1).
template<int CIN, bool BF16IN>
__global__ __launch_bounds__(512) void conv_mfma_u(const void* __restrict__ in,
    const float* __restrict__ w, const float* __restrict__ bias,
    unsigned* __restrict__ outu) {
  const int bx = blockIdx.x, by = blockIdx.y, b = blockIdx.z;
  const int tid = threadIdx.x;
  const int gy0 = by * 32, gx0 = bx * 32;
  __shared__ unsigned short sT[34 * 34 * 16];

  const int lane = tid & 63;
  const int g = lane >> 4;        // k-quarter 0..3
  const int co = lane & 15;       // output channel col
  bf16x8 Bf[5];
  #pragma unroll
  for (int P = 0; P < 5; ++P) {
    #pragma unroll
    for (int j = 0; j < 8; ++j) {
      const int tap = 2 * P + (g >> 1);
      const int ci = ((g & 1) << 3) + j;
      unsigned short v = 0;
      if (co < 10 && ci < CIN && tap < 9)
        v = f2bf(w[(co * CIN + ci) * 9 + tap]);
      Bf[P][j] = (short)v;
    }
  }
  const float bs = (co < 10) ? bias[co] : 0.f;

  for (int p = tid; p < 34 * 34; p += 512) {
    const int ly = p / 34, lx = p - ly * 34;
    const int gy = gy0 + ly - 1, gx = gx0 + lx - 1;
    const bool ok = ((unsigned)gy < HH) && ((unsigned)gx < WW);
    const int pix = gy * WW + gx;
    unsigned u[8];
    if (BF16IN) {
      const unsigned* pp = (const unsigned*)in + (size_t)b * 5 * HW + pix;
      #pragma unroll
      for (int c2 = 0; c2 < 8; ++c2)
        u[c2] = (c2 < (CIN + 1) / 2 && ok) ? pp[c2 * HW] : 0u;
    } else {
      const float* pp = (const float*)in + (size_t)b * CIN * HW + pix;
      #pragma unroll
      for (int c2 = 0; c2 < 8; ++c2) {
        float f0 = (2 * c2 < CIN && ok) ? pp[(2 * c2) * HW] : 0.f;
        float f1 = (2 * c2 + 1 < CIN && ok) ? pp[(2 * c2 + 1) * HW] : 0.f;
        u[c2] = pack2(f0, f1);
      }
    }
    uint4* dst = reinterpret_cast<uint4*>(&sT[p * 16]);
    dst[0] = make_uint4(u[0], u[1], u[2], u[3]);
    dst[1] = make_uint4(u[4], u[5], u[6], u[7]);
  }
  __syncthreads();

  const int wave = tid >> 6;
  unsigned* ob = outu + (size_t)b * 5 * HW;
  for (int i = 0; i < 8; ++i) {
    const int t = wave * 8 + i;
    const int py = t >> 1;
    const int pxb = (t & 1) << 4;
    f32x4 acc = {bs, bs, bs, bs};
    #pragma unroll
    for (int P = 0; P < 5; ++P) {
      int tap = 2 * P + (g >> 1);
      if (tap > 8) tap = 8;         // phantom tap: B=0 there
      const int dy = tap / 3 - 1, dx = tap % 3 - 1;
      const int m = lane & 15;
      const int addr = ((py + 1 + dy) * 34 + (pxb + m + 1 + dx)) * 16 + ((g & 1) << 3);
      bf16x8 a = *reinterpret_cast<const bf16x8*>(&sT[addr]);
      acc = __builtin_amdgcn_mfma_f32_16x16x32_bf16(a, Bf[P], acc, 0, 0, 0);
    }
    float o0 = fmaxf(acc[0], 0.f), o1 = fmaxf(acc[1], 0.f);
    float o2 = fmaxf(acc[2], 0.f), o3 = fmaxf(acc[3], 0.f);
    const float q0 = __shfl_xor(o0, 1), q1 = __shfl_xor(o1, 1);
    const float q2 = __shfl_xor(o2, 1), q3 = __shfl_xor(o3, 1);
    if (!(co & 1) && co < 10) {
      const int y = gy0 + py;
      const int x = gx0 + pxb + (g << 2);
      uint4 st;
      st.x = pack2(o0, q0); st.y = pack2(o1, q1);
      st.z = pack2(o2, q2); st.w = pack2(o3, q3);
      *reinterpret_cast<uint4*>(&ob[(co >> 1) * HW + y * WW + x]) = st;
    }
  }
}

// ---------------- final conv (10->5) via MFMA + bf16 imfeat build + cent0
// imfeat = 5 bf16-pair dword planes: p0=(c0,c1) p1=(c2,c3) p2=(c4,X0) p3=(X1,X2) p4=(x,y)*ck
__global__ __launch_bounds__(512) void conv_final_mfma(const unsigned* __restrict__ in,
    const float* __restrict__ w, const float* __restrict__ bias,
    const float* __restrict__ X, unsigned* __restrict__ imfeat,
    float* __restrict__ cent0) {
  const int bx = blockIdx.x, by = blockIdx.y, b = blockIdx.z;
  const int tid = threadIdx.x;
  const int gy0 = by * 32, gx0 = bx * 32;
  __shared__ unsigned short sT[34 * 34 * 16];
  __shared__ float sC[8][5];
  __shared__ float sX[8][3];

  const int lane = tid & 63;
  const int g = lane >> 4;
  const int co = lane & 15;
  bf16x8 Bf[5];
  #pragma unroll
  for (int P = 0; P < 5; ++P) {
    #pragma unroll
    for (int j = 0; j < 8; ++j) {
      const int tap = 2 * P + (g >> 1);
      const int ci = ((g & 1) << 3) + j;
      unsigned short v = 0;
      if (co < 5 && ci < 10 && tap < 9)
        v = f2bf(w[(co * 10 + ci) * 9 + tap]);
      Bf[P][j] = (short)v;
    }
  }
  const float bs = (co < 5) ? bias[co] : 0.f;

  for (int p = tid; p < 34 * 34; p += 512) {
    const int ly = p / 34, lx = p - ly * 34;
    const int gy = gy0 + ly - 1, gx = gx0 + lx - 1;
    const bool ok = ((unsigned)gy < HH) && ((unsigned)gx < WW);
    const unsigned* pp = in + (size_t)b * 5 * HW + gy * WW + gx;
    unsigned u[5];
    #pragma unroll
    for (int c2 = 0; c2 < 5; ++c2) u[c2] = ok ? pp[c2 * HW] : 0u;
    uint4* dst = reinterpret_cast<uint4*>(&sT[p * 16]);
    dst[0] = make_uint4(u[0], u[1], u[2], u[3]);
    dst[1] = make_uint4(u[4], 0u, 0u, 0u);
  }
  __syncthreads();

  const int wave = tid >> 6;
  unsigned* ob = imfeat + (size_t)b * 5 * HW;
  const float* Xb = X + (size_t)b * 3 * HW;
  float cSum = 0.f;
  for (int i = 0; i < 8; ++i) {
    const int t = wave * 8 + i;
    const int py = t >> 1;
    const int pxb = (t & 1) << 4;
    f32x4 acc = {bs, bs, bs, bs};
    #pragma unroll
    for (int P = 0; P < 5; ++P) {
      int tap = 2 * P + (g >> 1);
      if (tap > 8) tap = 8;
      const int dy = tap / 3 - 1, dx = tap % 3 - 1;
      const int m = lane & 15;
      const int addr = ((py + 1 + dy) * 34 + (pxb + m + 1 + dx)) * 16 + ((g & 1) << 3);
      bf16x8 a = *reinterpret_cast<const bf16x8*>(&sT[addr]);
      acc = __builtin_amdgcn_mfma_f32_16x16x32_bf16(a, Bf[P], acc, 0, 0, 0);
    }
    const int y = gy0 + py;
    const int x = gx0 + pxb + (g << 2);
    const float q0 = __shfl_xor(acc[0], 1), q1 = __shfl_xor(acc[1], 1);
    const float q2 = __shfl_xor(acc[2], 1), q3 = __shfl_xor(acc[3], 1);
    if (co == 0 || co == 2) {        // planes 0,1 = (c0,c1),(c2,c3)
      uint4 st;
      st.x = pack2(acc[0], q0); st.y = pack2(acc[1], q1);
      st.z = pack2(acc[2], q2); st.w = pack2(acc[3], q3);
      *reinterpret_cast<uint4*>(&ob[(co >> 1) * HW + y * WW + x]) = st;
    } else if (co == 4) {            // plane 2 = (c4, X0)
      float4 xv = *reinterpret_cast<const float4*>(&Xb[y * WW + x]);
      uint4 st;
      st.x = pack2(acc[0], xv.x); st.y = pack2(acc[1], xv.y);
      st.z = pack2(acc[2], xv.z); st.w = pack2(acc[3], xv.w);
      *reinterpret_cast<uint4*>(&ob[2 * HW + y * WW + x]) = st;
    }
    cSum += acc[0] + acc[1] + acc[2] + acc[3];
  }
  cSum += __shfl_xor(cSum, 16);
  cSum += __shfl_xor(cSum, 32);
  if (lane < 5) sC[wave][lane] = cSum;

  // planes 3,4 + X sums (2 px per thread)
  float xs[3] = {0.f, 0.f, 0.f};
  for (int p = tid; p < 1024; p += 512) {
    const int y = gy0 + (p >> 5), x = gx0 + (p & 31);
    const int pix = y * WW + x;
    float x0 = Xb[pix];
    float x1 = Xb[HW + pix];
    float x2 = Xb[2 * HW + pix];
    xs[0] += x0; xs[1] += x1; xs[2] += x2;
    ob[3 * HW + pix] = pack2(x1, x2);
    ob[4 * HW + pix] = pack2((float)x * CKXY, (float)y * CKXY);
  }
  #pragma unroll
  for (int off = 32; off; off >>= 1) {
    #pragma unroll
    for (int c = 0; c < 3; ++c) xs[c] += __shfl_down(xs[c], off);
  }
  if (lane == 0) {
    #pragma unroll
    for (int c = 0; c < 3; ++c) sX[wave][c] = xs[c];
  }
  __syncthreads();
  if (tid < 5) {
    float s = 0.f;
    #pragma unroll
    for (int wv = 0; wv < 8; ++wv) s += sC[wv][tid];
    cent0[((b * 10 + tid) * 16 + by) * 16 + bx] = s * (1.0f / 1024.0f);
  }
  if (tid >= 64 && tid < 67) {
    const int c = tid - 64;
    float s = 0.f;
    #pragma unroll
    for (int wv = 0; wv < 8; ++wv) s += sX[wv][c];
    cent0[((b * 10 + 5 + c) * 16 + by) * 16 + bx] = s * (1.0f / 1024.0f);
  }
  if (tid == 128) cent0[((b * 10 + 8) * 16 + by) * 16 + bx] = ((float)gx0 + 15.5f) * CKXY;
  if (tid == 129) cent0[((b * 10 + 9) * 16 + by) * 16 + bx] = ((float)gy0 + 15.5f) * CKXY;
}

// -------------------- SSN iteration: bf16 imfeat in, aff + block sums
__global__ __launch_bounds__(256) void iter2(const unsigned* __restrict__ imfeat,
    const float* __restrict__ centIn, const float* __restrict__ numP,
    const float* __restrict__ denP, float* __restrict__ numO,
    float* __restrict__ denO, float* __restrict__ affO) {
  const int cx = blockIdx.x, cy = blockIdx.y, b = blockIdx.z;
  const int tid = threadIdx.x;
  __shared__ float sc[9][10];
  __shared__ float nb[9][11];
  if (centIn) {
    if (tid < 90) {
      int s = tid / 10, ch = tid - s * 10;
      int dr = s / 3 - 1, dc = s % 3 - 1;
      int r = min(max(cy + dr, 0), 15), c = min(max(cx + dc, 0), 15);
      sc[s][ch] = centIn[((b * 10 + ch) * 16 + r) * 16 + c];
    }
    __syncthreads();
  } else {
    if (tid < 99) {
      int s = tid / 11, j = tid - s * 11;
      int dr = s / 3 - 1, dc = s % 3 - 1;
      int r = min(max(cy + dr, 0), 15), c = min(max(cx + dc, 0), 15);
      float a = 0.f;
      #pragma unroll
      for (int rr = -1; rr <= 1; ++rr)
        #pragma unroll
        for (int cc = -1; cc <= 1; ++cc) {
          int R = r + rr, C = c + cc;
          if ((unsigned)R < 16u && (unsigned)C < 16u)
            a += (j < 10) ? numP[((b * 10 + j) * 16 + R) * 16 + C]
                          : denP[(b * 16 + R) * 16 + C];
        }
      nb[s][j] = a;
    }
    __syncthreads();
    if (tid < 90) {
      int s = tid / 10, ch = tid - s * 10;
      sc[s][ch] = nb[s][ch] / nb[s][10];
    }
    __syncthreads();
  }

  float accN[10];
  #pragma unroll
  for (int ch = 0; ch < 10; ++ch) accN[ch] = 0.f;
  float accD = 0.f;
  const int col = tid & 31, row0 = tid >> 5;
  for (int p = 0; p < 4; ++p) {
    const int y = cy * 32 + row0 + p * 8;
    const int x = cx * 32 + col;
    const unsigned* fb = imfeat + (size_t)b * 5 * HW + y * WW + x;
    float f[10];
    #pragma unroll
    for (int c2 = 0; c2 < 5; ++c2) {
      unsigned u = fb[c2 * HW];
      f[2 * c2]     = __uint_as_float(u << 16);
      f[2 * c2 + 1] = __uint_as_float(u & 0xFFFF0000u);
    }
    float asum = 0.f;
    #pragma unroll
    for (int s = 0; s < 9; ++s) {
      float ss = 0.f;
      #pragma unroll
      for (int ch = 0; ch < 10; ++ch) { float d = f[ch] - sc[s][ch]; ss = fmaf(d, d, ss); }
      float a = __expf(-ss * (1.0f / 1000.0f));
      asum += a;
      if (affO) affO[((b * 9 + s) * HH + y) * WW + x] = a;
    }
    accD += asum;
    #pragma unroll
    for (int ch = 0; ch < 10; ++ch) accN[ch] = fmaf(f[ch], asum, accN[ch]);
  }
  #pragma unroll
  for (int off = 32; off; off >>= 1) {
    accD += __shfl_down(accD, off);
    #pragma unroll
    for (int ch = 0; ch < 10; ++ch) accN[ch] += __shfl_down(accN[ch], off);
  }
  __shared__ float sPart[4][11];
  const int wave = tid >> 6, lane = tid & 63;
  if (lane == 0) {
    #pragma unroll
    for (int ch = 0; ch < 10; ++ch) sPart[wave][ch] = accN[ch];
    sPart[wave][10] = accD;
  }
  __syncthreads();
  if (tid < 11) {
    float s = sPart[0][tid] + sPart[1][tid] + sPart[2][tid] + sPart[3][tid];
    if (tid < 10) numO[((b * 10 + tid) * 16 + cy) * 16 + cx] = s;
    else denO[(b * 16 + cy) * 16 + cx] = s;
  }
}

// ------------------------------- final cent = box3(num)/box3(den) -> output
__global__ __launch_bounds__(256) void cent_final(const float* __restrict__ num_bs,
    const float* __restrict__ den_bs, float* __restrict__ out_cent) {
  const int b = blockIdx.x;
  const int tid = threadIdx.x;
  const int cy = tid >> 4, cx = tid & 15;
  float den = 0.f;
  #pragma unroll
  for (int dr = -1; dr <= 1; ++dr)
    #pragma unroll
    for (int dc = -1; dc <= 1; ++dc) {
      int r = cy + dr, c = cx + dc;
      if ((unsigned)r < 16 && (unsigned)c < 16) den += den_bs[(b * 16 + r) * 16 + c];
    }
  #pragma unroll
  for (int ch = 0; ch < 10; ++ch) {
    float num = 0.f;
    #pragma unroll
    for (int dr = -1; dr <= 1; ++dr)
      #pragma unroll
      for (int dc = -1; dc <= 1; ++dc) {
        int r = cy + dr, c = cx + dc;
        if ((unsigned)r < 16 && (unsigned)c < 16)
          num += num_bs[((b * 10 + ch) * 16 + r) * 16 + c];
      }
    float invck = (ch >= 8) ? (1.0f / CKXY) : 1.0f;
    out_cent[((b * 10 + ch) * 16 + cy) * 16 + cx] = (num / den) * invck;
  }
}

// ---------------------------------------------------------------------------
extern "C" void kernel_launch(void* const* d_in, const int* in_sizes, int n_in,
                              void* d_out, int out_size, void* d_ws, size_t ws_size,
                              hipStream_t stream) {
  const float* X      = (const float*)d_in[0];
  const float* w0     = (const float*)d_in[1];
  const float* b0     = (const float*)d_in[2];
  const float* ws_mid = (const float*)d_in[3];
  const float* bs_mid = (const float*)d_in[4];
  const float* wf     = (const float*)d_in[5];
  const float* bf     = (const float*)d_in[6];
  float* out = (float*)d_out;

  const size_t uplane = (size_t)BB * 5 * HW;    // bf16 pair-planes (dwords)
  unsigned* uA     = (unsigned*)d_ws;
  unsigned* uB     = uA + uplane;
  unsigned* imfeat = uB + uplane;
  float* num0      = (float*)(imfeat + uplane);
  float* den0      = num0 + BB * 10 * 256;
  float* num1      = den0 + BB * 256;
  float* den1      = num1 + BB * 10 * 256;
  float* centA     = den1 + BB * 256;

  dim3 cgrid(16, 16, BB);   // 32x32 tiles
  conv_mfma_u<3, false><<<cgrid, 512, 0, stream>>>(X, w0, b0, uA);
  const unsigned* cur = uA;
  unsigned* nxt = uB;
  for (int l = 0; l < 8; ++l) {
    conv_mfma_u<10, true><<<cgrid, 512, 0, stream>>>(cur, ws_mid + l * 900, bs_mid + l * 10, nxt);
    const unsigned* t = cur; cur = nxt; nxt = (unsigned*)t;
  }
  // cur == uA after 8 swaps
  conv_final_mfma<<<cgrid, 512, 0, stream>>>(cur, wf, bf, X, imfeat, centA);

  float* aff_out = out + BB * 10 * 256;  // cent (5120) then aff
  float* nums[2] = {num0, num1};
  float* dens[2] = {den0, den1};
  for (int k = 0; k < 10; ++k) {
    iter2<<<cgrid, 256, 0, stream>>>(imfeat,
        (k == 0) ? centA : nullptr,
        (k == 0) ? nullptr : nums[(k - 1) & 1],
        (k == 0) ? nullptr : dens[(k - 1) & 1],
        nums[k & 1], dens[k & 1],
        (k == 9) ? aff_out : nullptr);
  }
  cent_final<<<dim3(BB), 256, 0, stream>>>(nums[1], dens[1], out);
}